// Round 2
// 132.745 us; speedup vs baseline: 1.0003x; 1.0003x over previous
//
#include <hip/hip_runtime.h>
#include <math.h>

#define NB 32
#define CC 512
#define HW 1024
#define NJ 10

// Inter-kernel gap buffer lives in module device memory, NOT d_ws.
// K1 fully overwrites it every invocation before K2 reads it, so there is
// no stale-state dependence across iterations/replays.
__device__ float g_gap[NB * CC];

__device__ __forceinline__ float wave_reduce(float s) {
#pragma unroll
  for (int off = 32; off; off >>= 1) s += __shfl_down(s, off, 64);
  return s;
}

// K1: gap[n,c] = mean over HW. 1024 blocks x 256 threads; each wave reduces
// 4 rows (4 outstanding float4 loads per lane per row for MLP).
// Side effect we rely on: this pass pulls all of x (67 MB) into the 256 MB
// L3, so K2's re-read is L3-resident.
__global__ __launch_bounds__(256) void k_gap(const float* __restrict__ x) {
  int wv = threadIdx.x >> 6, lane = threadIdx.x & 63;
  int r0 = blockIdx.x * 16;
#pragma unroll
  for (int it = 0; it < 4; ++it) {
    int row = r0 + wv * 4 + it;
    const float4* xp = (const float4*)x + (size_t)row * 256;
    float s = 0.f;
#pragma unroll
    for (int k = 0; k < 4; ++k) {
      float4 v = xp[lane + 64 * k];
      s += v.x + v.y + v.z + v.w;
    }
    s = wave_reduce(s);
    if (lane == 0) g_gap[row] = s * (1.0f / 1024.0f);
  }
}

// K2: fully fused q/softmax-moments/output.
// Block = (n, pblk): all 512 channels x 64 spatial positions.
// Thread (cg,pg): holds x[cg*16..+15][pg*4..+3] in registers (16 float4).
//   phase Q: q=sigmoid(conv5(gap)), P_j partial sums -> invZ (redundant/block)
//   phase B: acc_j = sum_i q^j * xv[i]; reduce over cg (shfl-xor + LDS tree)
//            -> sfin[pg][j] = invZ*(1/j!)*s_j  (final for this p-slice)
//   phase C: out = xv[i] * sum_j sfin[pg][j] * q_d^j   (x never re-read)
__global__ __launch_bounds__(512) void k_fused(const float* __restrict__ x,
                                               const float* __restrict__ wq,
                                               const float* __restrict__ bq,
                                               float* __restrict__ out) {
  int n = blockIdx.x >> 4, pblk = blockIdx.x & 15;
  int t = threadIdx.x;
  int cg = t >> 4, pg = t & 15;
  int wv = t >> 6, lane = t & 63;

  __shared__ float qs[CC];
  __shared__ float wred[8][NJ];
  __shared__ float4 sred[8][16][NJ + 1];  // +1 float4 pad: no 4-way conflict
  __shared__ float4 sfin[16][NJ + 1];
  __shared__ float invZ_sh;

  const float cj[NJ] = {1.f, 1.f, 0.5f, 1.f / 6.f, 1.f / 24.f, 1.f / 120.f,
                        1.f / 720.f, 1.f / 5040.f, 1.f / 40320.f, 1.f / 362880.f};

  // ---- load x tile into registers (read x exactly once in this kernel) ----
  float4 xv[16];
  const float4* x4 = (const float4*)x;
  size_t base = (size_t)(n * CC + cg * 16) * 256 + (size_t)pblk * 16 + pg;
#pragma unroll
  for (int i = 0; i < 16; ++i) xv[i] = x4[base + (size_t)i * 256];

  // ---- phase Q: q = sigmoid(conv5(gap)+b); wave partials of P_j ----
  {
    int c = t;  // 512 threads == 512 channels
    const float* g = g_gap + n * CC;
    float z = bq[0];
#pragma unroll
    for (int k = 0; k < 5; ++k) {
      int idx = c + k - 2;
      float gv = (idx >= 0 && idx < CC) ? g[idx] : 0.f;
      z = fmaf(gv, wq[k], z);
    }
    float qv = 1.f / (1.f + expf(-z));
    qs[c] = qv;
    float pj[NJ];
    float pw = 1.f;
#pragma unroll
    for (int j = 0; j < NJ; ++j) { pj[j] = pw; pw *= qv; }
#pragma unroll
    for (int j = 0; j < NJ; ++j) pj[j] = wave_reduce(pj[j]);
    if (lane == 0) {
#pragma unroll
      for (int j = 0; j < NJ; ++j) wred[wv][j] = pj[j];
    }
  }
  __syncthreads();
  if (t == 0) {
    float Z = 0.f;
#pragma unroll
    for (int j = 0; j < NJ; ++j) {
      float P = 0.f;
#pragma unroll
      for (int w8 = 0; w8 < 8; ++w8) P += wred[w8][j];
      Z = fmaf(cj[j] * P, P, Z);
    }
    invZ_sh = 1.f / Z;  // read after the NEXT __syncthreads
  }

  // ---- phase B: per-thread moment accumulation over 16 channels ----
  float4 acc[NJ];
#pragma unroll
  for (int j = 0; j < NJ; ++j) acc[j] = make_float4(0.f, 0.f, 0.f, 0.f);
#pragma unroll
  for (int i = 0; i < 16; ++i) {
    float qc = qs[cg * 16 + i];
    float4 v = xv[i];
    float w = 1.f;
#pragma unroll
    for (int j = 0; j < NJ; ++j) {
      acc[j].x = fmaf(w, v.x, acc[j].x);
      acc[j].y = fmaf(w, v.y, acc[j].y);
      acc[j].z = fmaf(w, v.z, acc[j].z);
      acc[j].w = fmaf(w, v.w, acc[j].w);
      w *= qc;
    }
  }
  // reduce over the 4 cg within this wave (lane bits 4,5)
#pragma unroll
  for (int j = 0; j < NJ; ++j) {
    acc[j].x += __shfl_xor(acc[j].x, 16, 64);
    acc[j].y += __shfl_xor(acc[j].y, 16, 64);
    acc[j].z += __shfl_xor(acc[j].z, 16, 64);
    acc[j].w += __shfl_xor(acc[j].w, 16, 64);
    acc[j].x += __shfl_xor(acc[j].x, 32, 64);
    acc[j].y += __shfl_xor(acc[j].y, 32, 64);
    acc[j].z += __shfl_xor(acc[j].z, 32, 64);
    acc[j].w += __shfl_xor(acc[j].w, 32, 64);
  }
  if (lane < 16) {
#pragma unroll
    for (int j = 0; j < NJ; ++j) sred[wv][lane][j] = acc[j];
  }
  __syncthreads();
  // cross-wave tree: 160 bins (16 pg x 10 j), fold in invZ * 1/j!
  if (t < 160) {
    int pp = t / NJ, j = t - pp * NJ;
    float4 a = make_float4(0.f, 0.f, 0.f, 0.f);
#pragma unroll
    for (int w8 = 0; w8 < 8; ++w8) {
      float4 v = sred[w8][pp][j];
      a.x += v.x; a.y += v.y; a.z += v.z; a.w += v.w;
    }
    float sc = cj[j] * invZ_sh;
    a.x *= sc; a.y *= sc; a.z *= sc; a.w *= sc;
    sfin[pp][j] = a;
  }
  __syncthreads();

  // ---- phase C: out = x * att, x still in registers ----
  float4 sj[NJ];
#pragma unroll
  for (int j = 0; j < NJ; ++j) sj[j] = sfin[pg][j];
  float4* o4 = (float4*)out;
#pragma unroll
  for (int i = 0; i < 16; ++i) {
    float qd = qs[cg * 16 + i];
    float w = 1.f;
    float4 att = make_float4(0.f, 0.f, 0.f, 0.f);
#pragma unroll
    for (int j = 0; j < NJ; ++j) {
      att.x = fmaf(w, sj[j].x, att.x);
      att.y = fmaf(w, sj[j].y, att.y);
      att.z = fmaf(w, sj[j].z, att.z);
      att.w = fmaf(w, sj[j].w, att.w);
      w *= qd;
    }
    float4 xvv = xv[i];
    float4 o;
    o.x = xvv.x * att.x; o.y = xvv.y * att.y;
    o.z = xvv.z * att.z; o.w = xvv.w * att.w;
    o4[base + (size_t)i * 256] = o;
  }
}

extern "C" void kernel_launch(void* const* d_in, const int* in_sizes, int n_in,
                              void* d_out, int out_size, void* d_ws, size_t ws_size,
                              hipStream_t stream) {
  const float* x  = (const float*)d_in[0];
  const float* wq = (const float*)d_in[1];
  const float* bq = (const float*)d_in[2];
  float* out = (float*)d_out;
  (void)d_ws; (void)ws_size;  // workspace intentionally unused

  k_gap<<<NB * CC / 16, 256, 0, stream>>>(x);
  k_fused<<<NB * 16, 512, 0, stream>>>(x, wq, bq, out);
}